// Round 9
// baseline (1499.361 us; speedup 1.0000x reference)
//
#include <hip/hip_runtime.h>
#include <math.h>

#define HD 8192
#define ID 4096
#define KSEL 409           // int(8192 * 0.05)
#define LR 0.001f
#define NBLK 1024
#define NTHR 256
#define ENC_BLKS 341       // blocks 1..341 enc; 342..1023 ssq; 0 topk
#define SSQ_BLKS (NBLK - ENC_BLKS - 1)   // 682

typedef float f4 __attribute__((ext_vector_type(4)));
typedef float f2 __attribute__((ext_vector_type(2)));

// workspace layout (float indices)
#define WS_H     0                 // 8192 f32
#define WS_HS    8192              // 8192 f32
#define WS_IDX   16384             // 8192 i32
#define WS_VAL   24576             // 8192 f32
#define WS_SCAL  32768             // [0]=kth, [1]=inv_norm, [2](int)=n
#define WS_SSQ   32832             // 1024 doubles, one per block (byte 131328)
#define WS_FPART (32832 + 2048)    // 128 doubles: 32 blocks x {dy,sh2,l0,l1}
#define WS_BAR   (32832 + 2048 + 256)  // u32: [0]=gbar, [1]=ctrA, [2]=ctrB, [3]=invflag

__device__ __forceinline__ unsigned ld_poll(unsigned* p) {
    return __hip_atomic_load(p, __ATOMIC_ACQUIRE, __HIP_MEMORY_SCOPE_AGENT);
}

__global__ __launch_bounds__(NTHR, 4) void k_fused(
    const float* __restrict__ x,  const float* __restrict__ W,
    const float* __restrict__ b,  const float* __restrict__ S,
    const float* __restrict__ st, const float* __restrict__ Wc,
    const float* __restrict__ bc, float* __restrict__ out,
    float* __restrict__ ws) {
    __shared__ f4 smem4[1024];      // 16 KB (x staging / PB idx+val)
    __shared__ double sd[256];
    __shared__ int sred[4];
    __shared__ int wsum[4];
    const int tid = threadIdx.x;
    const int bid = blockIdx.x;
    unsigned* bar  = (unsigned*)ws + WS_BAR;
    unsigned* ctrA = (unsigned*)ws + WS_BAR + 1;
    unsigned* ctrB = (unsigned*)ws + WS_BAR + 2;
    unsigned* invf = (unsigned*)ws + WS_BAR + 3;

    // ===== PA: enc (1..341, NT loads) || ssq (342..1023) || topk (0, waits enc) =====
    if (bid >= 1 && bid <= ENC_BLKS) {
        const f4* x4 = (const f4*)x;
        for (int k = tid; k < ID / 4; k += NTHR) smem4[k] = x4[k];
        __syncthreads();
        int wave = tid >> 6, lane = tid & 63;
        int wenc = (bid - 1) * 4 + wave;               // 0..1363
        for (int row = wenc; row < HD; row += ENC_BLKS * 4) {
            const f4* w4 = (const f4*)(W + (size_t)row * ID);
            float acc = 0.f;
#pragma unroll
            for (int k = 0; k < 16; ++k) {
                f4 a  = __builtin_nontemporal_load(&w4[lane + 64 * k]);  // keep S in L3
                f4 xv = smem4[lane + 64 * k];
                acc += a.x * xv.x + a.y * xv.y + a.z * xv.z + a.w * xv.w;
            }
#pragma unroll
            for (int off = 32; off; off >>= 1) acc += __shfl_xor(acc, off, 64);
            if (lane == 0) {
                float h = acc + b[row];
                ws[WS_H + row] = h > 0.f ? h : 0.f;
            }
        }
        if (tid == 0) ((double*)(ws + WS_SSQ))[bid] = 0.0;
        __syncthreads();
        if (tid == 0) {
            __threadfence();
            __hip_atomic_fetch_add(ctrA, 1u, __ATOMIC_RELEASE, __HIP_MEMORY_SCOPE_AGENT);
        }
    } else if (bid > ENC_BLKS) {
        const f4* S4 = (const f4*)S;
        const int total4 = HD * HD / 4;                // 16777216
        const int TT = SSQ_BLKS * NTHR;                // 174592
        int i = (bid - ENC_BLKS - 1) * NTHR + tid;
        double a0 = 0, a1 = 0, a2 = 0, a3 = 0;
        for (; i + 3 * TT < total4; i += 4 * TT) {     // 4 loads in flight
            f4 v0 = S4[i], v1 = S4[i + TT], v2 = S4[i + 2 * TT], v3 = S4[i + 3 * TT];
            a0 += (double)(v0.x * v0.x + v0.y * v0.y) + (double)(v0.z * v0.z + v0.w * v0.w);
            a1 += (double)(v1.x * v1.x + v1.y * v1.y) + (double)(v1.z * v1.z + v1.w * v1.w);
            a2 += (double)(v2.x * v2.x + v2.y * v2.y) + (double)(v2.z * v2.z + v2.w * v2.w);
            a3 += (double)(v3.x * v3.x + v3.y * v3.y) + (double)(v3.z * v3.z + v3.w * v3.w);
        }
        for (; i < total4; i += TT) {
            f4 v0 = S4[i];
            a0 += (double)(v0.x * v0.x + v0.y * v0.y) + (double)(v0.z * v0.z + v0.w * v0.w);
        }
        sd[tid] = (a0 + a1) + (a2 + a3);
        __syncthreads();
        for (int s = 128; s; s >>= 1) {
            if (tid < s) sd[tid] += sd[tid + s];
            __syncthreads();
        }
        if (tid == 0) ((double*)(ws + WS_SSQ))[bid] = sd[0];
        __syncthreads();
    } else {  // bid == 0: wait for enc, then exact top-K + compaction
        if (tid == 0) {
            while (ld_poll(ctrA) < (unsigned)ENC_BLKS) __builtin_amdgcn_s_sleep(2);
            __threadfence();
            ((double*)(ws + WS_SSQ))[0] = 0.0;
        }
        __syncthreads();
        float v[32];
        const f4* h4 = (const f4*)(ws + WS_H);
#pragma unroll
        for (int k = 0; k < 8; ++k) {
            f4 t = h4[tid * 8 + k];
            v[4 * k + 0] = t.x; v[4 * k + 1] = t.y; v[4 * k + 2] = t.z; v[4 * k + 3] = t.w;
        }
        // h >= 0 -> float order == uint bit order; exact Kth via bit binary search
        unsigned lo = 0u, hi = 0x7F800000u;
        while (hi - lo > 1u) {
            unsigned mid = (lo + hi) >> 1;
            float t = __uint_as_float(mid);
            int c = 0;
#pragma unroll
            for (int k = 0; k < 32; ++k) c += (v[k] >= t) ? 1 : 0;
#pragma unroll
            for (int off = 32; off; off >>= 1) c += __shfl_xor(c, off, 64);
            if ((tid & 63) == 0) sred[tid >> 6] = c;
            __syncthreads();
            int cnt = sred[0] + sred[1] + sred[2] + sred[3];
            __syncthreads();
            if (cnt >= KSEL) lo = mid; else hi = mid;
        }
        float kth = __uint_as_float(lo);

        int cnt_t = 0;
        f4* hs4 = (f4*)(ws + WS_HS);
#pragma unroll
        for (int k = 0; k < 8; ++k) {
            f4 o;
            o.x = (v[4 * k + 0] >= kth) ? v[4 * k + 0] : 0.f;
            o.y = (v[4 * k + 1] >= kth) ? v[4 * k + 1] : 0.f;
            o.z = (v[4 * k + 2] >= kth) ? v[4 * k + 2] : 0.f;
            o.w = (v[4 * k + 3] >= kth) ? v[4 * k + 3] : 0.f;
            hs4[tid * 8 + k] = o;
        }
#pragma unroll
        for (int k = 0; k < 32; ++k) cnt_t += ((v[k] >= kth) && (v[k] > 0.f)) ? 1 : 0;

        int c = cnt_t;
#pragma unroll
        for (int off = 1; off < 64; off <<= 1) {
            int y = __shfl_up(c, off, 64);
            if ((tid & 63) >= off) c += y;
        }
        if ((tid & 63) == 63) wsum[tid >> 6] = c;
        __syncthreads();
        int base = 0;
        for (int w = 0; w < (tid >> 6); ++w) base += wsum[w];
        int p = base + c - cnt_t;

        int* idx = ((int*)ws) + WS_IDX;
#pragma unroll
        for (int k = 0; k < 32; ++k) {
            float val = v[k];
            if ((val >= kth) && (val > 0.f)) {
                idx[p] = tid * 32 + k;
                ws[WS_VAL + p] = val;
                ++p;
            }
        }
        if (tid == 0) {
            ws[WS_SCAL + 0] = kth;
            ((int*)ws)[WS_SCAL + 2] = wsum[0] + wsum[1] + wsum[2] + wsum[3];
        }
        __syncthreads();
    }

    // ---- single full grid barrier (load-only polling) ----
    __syncthreads();
    if (tid == 0) {
        __threadfence();
        __hip_atomic_fetch_add(bar, 1u, __ATOMIC_RELEASE, __HIP_MEMORY_SCOPE_AGENT);
        while (ld_poll(bar) < (unsigned)NBLK) __builtin_amdgcn_s_sleep(2);
        __threadfence();
    }
    __syncthreads();

    // ===== PB (blocks 0..31): y gather + tanh + out + partials;  PC: block 0 =====
    if (bid < 32) {
        int n = ((const int*)ws)[WS_SCAL + 2];
        int* sidx = (int*)smem4;                 // 8 KB
        float* sval = (float*)(smem4 + 512);     // 8 KB at byte offset 8192
        int nl = n < 2048 ? n : 2048;
        for (int t = tid; t < nl; t += NTHR) {
            sidx[t] = ((const int*)ws)[WS_IDX + t];
            sval[t] = ws[WS_VAL + t];
        }
        __syncthreads();
        int j = bid * NTHR + tid;               // 0..8191
        float y = 0.f;
#pragma unroll 4
        for (int t = 0; t < n; ++t) {
            int   ii = (t < 2048) ? sidx[t] : ((const int*)ws)[WS_IDX + t];
            float vv = (t < 2048) ? sval[t] : ws[WS_VAL + t];
            y += vv * S[(size_t)ii * HD + j];   // L3-resident rows
        }
        float hsj = ws[WS_HS + j];
        float ns = tanhf(y + st[j]);
        out[2 + j] = ns;
        double red[4];
        red[0] = (double)(y * hsj);
        red[1] = (double)(hsj * hsj);
        red[2] = (double)(ns * Wc[j]);
        red[3] = (double)(ns * Wc[HD + j]);
        __syncthreads();
        for (int q = 0; q < 4; ++q) {
            sd[tid] = red[q];
            __syncthreads();
            for (int s = 128; s; s >>= 1) {
                if (tid < s) sd[tid] += sd[tid + s];
                __syncthreads();
            }
            if (tid == 0) ((double*)(ws + WS_FPART))[bid * 4 + q] = sd[0];
            __syncthreads();
        }
        if (tid == 0 && bid != 0) {
            __threadfence();
            __hip_atomic_fetch_add(ctrB, 1u, __ATOMIC_RELEASE, __HIP_MEMORY_SCOPE_AGENT);
        }
        if (bid == 0) {
            // ---- PC: combine -> inv_norm + logits ----
            if (tid == 0) {
                while (ld_poll(ctrB) < 31u) __builtin_amdgcn_s_sleep(2);
                __threadfence();
            }
            __syncthreads();
            double red5[5] = {0, 0, 0, 0, 0};
            const double* sp = (const double*)(ws + WS_SSQ);
            for (int i = tid; i < NBLK; i += NTHR) red5[4] += sp[i];
            const double* fp = (const double*)(ws + WS_FPART);
            if (tid < 32) {
                red5[0] = fp[tid * 4 + 0];
                red5[1] = fp[tid * 4 + 1];
                red5[2] = fp[tid * 4 + 2];
                red5[3] = fp[tid * 4 + 3];
            }
            __syncthreads();
            double tot[5];
            for (int q = 0; q < 5; ++q) {
                sd[tid] = red5[q];
                __syncthreads();
                for (int s = 128; s; s >>= 1) {
                    if (tid < s) sd[tid] += sd[tid + s];
                    __syncthreads();
                }
                tot[q] = sd[0];
                __syncthreads();
            }
            if (tid == 0) {
                // ||S + lr*hh^T||^2 = ||S||^2 + 2*lr*(h^T S h) + lr^2*(||h||^2)^2
                double n2 = tot[4] + 2.0 * (double)LR * tot[0]
                          + (double)LR * (double)LR * tot[1] * tot[1];
                ws[WS_SCAL + 1] = (float)(1.0 / sqrt(n2));
                out[0] = (float)(tot[2] + (double)bc[0]);
                out[1] = (float)(tot[3] + (double)bc[1]);
                __threadfence();
                __hip_atomic_store(invf, 1u, __ATOMIC_RELEASE, __HIP_MEMORY_SCOPE_AGENT);
            }
            __syncthreads();
        } else {
            if (tid == 0) {
                while (ld_poll(invf) == 0u) __builtin_amdgcn_s_sleep(2);
                __threadfence();
            }
            __syncthreads();
        }
    } else {
        if (tid == 0) {
            while (ld_poll(invf) == 0u) __builtin_amdgcn_s_sleep(2);
            __threadfence();
        }
        __syncthreads();
    }

    // ===== PD: scale+write, 8 rows/block, h-slice in VGPRs, NT stores =====
    {
        float inv = ws[WS_SCAL + 1];
        const f4* hs4g = (const f4*)(ws + WS_HS);
        f4 hreg[8];
#pragma unroll
        for (int it = 0; it < 8; ++it) hreg[it] = hs4g[it * NTHR + tid];
#pragma unroll 2
        for (int r = 0; r < 8; ++r) {
            int row = bid * 8 + r;
            float hi = ws[WS_HS + row] * LR;
            const f4* Srow = (const f4*)(S + (size_t)row * HD);
            float* o = out + 2 + HD + (size_t)row * HD;  // 8B-aligned -> f2 stores
            if (hi != 0.f) {
#pragma unroll
                for (int it = 0; it < 8; ++it) {
                    int j4 = it * NTHR + tid;
                    f4 s = Srow[j4];          // L3 hit (S resident; NT stores don't evict)
                    f4 h = hreg[it];
                    f2 a  = {(s.x + hi * h.x) * inv, (s.y + hi * h.y) * inv};
                    f2 bb = {(s.z + hi * h.z) * inv, (s.w + hi * h.w) * inv};
                    f2* o2 = (f2*)(o + (size_t)j4 * 4);
                    __builtin_nontemporal_store(a,  o2);
                    __builtin_nontemporal_store(bb, o2 + 1);
                }
            } else {
#pragma unroll
                for (int it = 0; it < 8; ++it) {
                    int j4 = it * NTHR + tid;
                    f4 s = Srow[j4];
                    f2 a  = {s.x * inv, s.y * inv};
                    f2 bb = {s.z * inv, s.w * inv};
                    f2* o2 = (f2*)(o + (size_t)j4 * 4);
                    __builtin_nontemporal_store(a,  o2);
                    __builtin_nontemporal_store(bb, o2 + 1);
                }
            }
        }
    }
}

extern "C" void kernel_launch(void* const* d_in, const int* in_sizes, int n_in,
                              void* d_out, int out_size, void* d_ws, size_t ws_size,
                              hipStream_t stream) {
    const float* x     = (const float*)d_in[0];
    const float* W_enc = (const float*)d_in[1];
    const float* b_enc = (const float*)d_in[2];
    const float* syn   = (const float*)d_in[3];
    const float* state = (const float*)d_in[4];
    const float* W_cls = (const float*)d_in[5];
    const float* b_cls = (const float*)d_in[6];
    float* out = (float*)d_out;
    float* ws  = (float*)d_ws;

    // reset barrier/counters/flag (graph-capturable async memset)
    hipMemsetAsync((char*)d_ws + (size_t)WS_BAR * 4, 0, 16, stream);
    hipLaunchKernelGGL(k_fused, dim3(NBLK), dim3(NTHR), 0, stream,
                       x, W_enc, b_enc, syn, state, W_cls, b_cls, out, ws);
}

// Round 10
// 225.272 us; speedup vs baseline: 6.6558x; 6.6558x over previous
//
#include <hip/hip_runtime.h>
#include <math.h>

#define HD 8192
#define ID 4096
#define KSEL 409           // int(8192 * 0.05)
#define LR 0.001f

typedef float f4 __attribute__((ext_vector_type(4)));
typedef float f2 __attribute__((ext_vector_type(2)));

// workspace layout (float indices)
#define WS_H     0                 // 8192 f32
#define WS_HS    8192              // 8192 f32
#define WS_IDX   16384             // 8192 i32
#define WS_VAL   24576             // 8192 f32
#define WS_SCAL  32768             // [0]=kth, [1]=inv_norm, [2](int)=n
#define WS_SSQ   32832             // 2048 doubles, one per ssq block (byte 131328)
#define WS_FPART (32832 + 4096)    // 128 doubles: 32 blocks x {dy,sh2,l0,l1}

// ---------- K1 fused: blocks [0,2048) ssq(S); [2048,4096) enc (NT W loads) ----------
__global__ __launch_bounds__(256) void k_main(const float* __restrict__ x,
                                              const float* __restrict__ W,
                                              const float* __restrict__ b,
                                              const float* __restrict__ S,
                                              float* __restrict__ ws) {
    int tid = threadIdx.x;
    if (blockIdx.x < 2048) {
        // ---- ssq: ascending stream, warms L3 with S ----
        const f4* S4 = (const f4*)S;
        int gid = blockIdx.x * 256 + tid;
        double acc = 0.0;
        const int total4 = HD * HD / 4;  // 16777216
        for (int i = gid; i < total4; i += 2048 * 256) {
            f4 v = S4[i];
            acc += (double)(v.x * v.x + v.y * v.y) + (double)(v.z * v.z + v.w * v.w);
        }
        __shared__ double sd[256];
        sd[tid] = acc;
        __syncthreads();
        for (int s = 128; s; s >>= 1) {
            if (tid < s) sd[tid] += sd[tid + s];
            __syncthreads();
        }
        if (tid == 0) ((double*)(ws + WS_SSQ))[blockIdx.x] = sd[0];
    } else {
        // ---- enc: 4 rows/block, NT loads keep W out of caches ----
        __shared__ f4 sx[ID / 4];
        const f4* x4 = (const f4*)x;
        for (int k = tid; k < ID / 4; k += 256) sx[k] = x4[k];
        __syncthreads();
        int wave = tid >> 6, lane = tid & 63;
        int row = (blockIdx.x - 2048) * 4 + wave;
        const f4* w4 = (const f4*)(W + (size_t)row * ID);
        float acc = 0.f;
#pragma unroll
        for (int k = 0; k < 16; ++k) {
            f4 a  = __builtin_nontemporal_load(&w4[lane + 64 * k]);
            f4 xv = sx[lane + 64 * k];
            acc += a.x * xv.x + a.y * xv.y + a.z * xv.z + a.w * xv.w;
        }
#pragma unroll
        for (int off = 32; off; off >>= 1) acc += __shfl_xor(acc, off, 64);
        if (lane == 0) {
            float h = acc + b[row];
            ws[WS_H + row] = h > 0.f ? h : 0.f;
        }
    }
}

// ---------- K2: exact top-K threshold (bit binary search) + compaction ----------
__global__ __launch_bounds__(256) void k_topk(float* __restrict__ ws) {
    int tid = threadIdx.x;
    float v[32];
    const f4* h4 = (const f4*)(ws + WS_H);
#pragma unroll
    for (int k = 0; k < 8; ++k) {
        f4 t = h4[tid * 8 + k];
        v[4 * k + 0] = t.x; v[4 * k + 1] = t.y; v[4 * k + 2] = t.z; v[4 * k + 3] = t.w;
    }
    __shared__ int sred[4];
    __shared__ int wsum[4];
    // h >= 0 (relu) -> float order == uint bit order. Find largest u with
    // count(h >= u) >= K: u is exactly the Kth-largest value.
    unsigned lo = 0u, hi = 0x7F800000u;
    while (hi - lo > 1u) {
        unsigned mid = (lo + hi) >> 1;
        float t = __uint_as_float(mid);
        int c = 0;
#pragma unroll
        for (int k = 0; k < 32; ++k) c += (v[k] >= t) ? 1 : 0;
#pragma unroll
        for (int off = 32; off; off >>= 1) c += __shfl_xor(c, off, 64);
        if ((tid & 63) == 0) sred[tid >> 6] = c;
        __syncthreads();
        int cnt = sred[0] + sred[1] + sred[2] + sred[3];
        __syncthreads();
        if (cnt >= KSEL) lo = mid; else hi = mid;
    }
    float kth = __uint_as_float(lo);

    int cnt_t = 0;
    f4* hs4 = (f4*)(ws + WS_HS);
#pragma unroll
    for (int k = 0; k < 8; ++k) {
        f4 o;
        o.x = (v[4 * k + 0] >= kth) ? v[4 * k + 0] : 0.f;
        o.y = (v[4 * k + 1] >= kth) ? v[4 * k + 1] : 0.f;
        o.z = (v[4 * k + 2] >= kth) ? v[4 * k + 2] : 0.f;
        o.w = (v[4 * k + 3] >= kth) ? v[4 * k + 3] : 0.f;
        hs4[tid * 8 + k] = o;
    }
#pragma unroll
    for (int k = 0; k < 32; ++k) cnt_t += ((v[k] >= kth) && (v[k] > 0.f)) ? 1 : 0;

    int c = cnt_t;
#pragma unroll
    for (int off = 1; off < 64; off <<= 1) {
        int y = __shfl_up(c, off, 64);
        if ((tid & 63) >= off) c += y;
    }
    if ((tid & 63) == 63) wsum[tid >> 6] = c;
    __syncthreads();
    int base = 0;
    for (int w = 0; w < (tid >> 6); ++w) base += wsum[w];
    int p = base + c - cnt_t;

    int* idx = ((int*)ws) + WS_IDX;
#pragma unroll
    for (int k = 0; k < 32; ++k) {
        float val = v[k];
        if ((val >= kth) && (val > 0.f)) {
            idx[p] = tid * 32 + k;
            ws[WS_VAL + p] = val;
            ++p;
        }
    }
    if (tid == 0) {
        ws[WS_SCAL + 0] = kth;
        ((int*)ws)[WS_SCAL + 2] = wsum[0] + wsum[1] + wsum[2] + wsum[3];
    }
}

// ---------- K3: y = h_sparse @ S (direct, L3-hot) + tanh + out + partials ----------
__global__ __launch_bounds__(256) void k_ymvfin(const float* __restrict__ S,
                                                const float* __restrict__ st,
                                                const float* __restrict__ Wc,
                                                float* __restrict__ ws,
                                                float* __restrict__ out) {
    __shared__ int   sidx[2048];
    __shared__ float sval[2048];
    __shared__ double sd[256];
    int tid = threadIdx.x;
    int n = ((const int*)ws)[WS_SCAL + 2];
    int nl = n < 2048 ? n : 2048;
    for (int t = tid; t < nl; t += 256) {
        sidx[t] = ((const int*)ws)[WS_IDX + t];
        sval[t] = ws[WS_VAL + t];
    }
    __syncthreads();
    int j = blockIdx.x * 256 + tid;   // 0..8191
    float y = 0.f;
#pragma unroll 4
    for (int t = 0; t < n; ++t) {
        int   ii = (t < 2048) ? sidx[t] : ((const int*)ws)[WS_IDX + t];
        float vv = (t < 2048) ? sval[t] : ws[WS_VAL + t];
        y += vv * S[(size_t)ii * HD + j];   // rows L3-resident from ssq
    }
    float hsj = ws[WS_HS + j];
    float ns = tanhf(y + st[j]);
    out[2 + j] = ns;
    double red[4];
    red[0] = (double)(y * hsj);
    red[1] = (double)(hsj * hsj);
    red[2] = (double)(ns * Wc[j]);
    red[3] = (double)(ns * Wc[HD + j]);
    for (int q = 0; q < 4; ++q) {
        sd[tid] = red[q];
        __syncthreads();
        for (int s = 128; s; s >>= 1) {
            if (tid < s) sd[tid] += sd[tid + s];
            __syncthreads();
        }
        if (tid == 0) ((double*)(ws + WS_FPART))[blockIdx.x * 4 + q] = sd[0];
        __syncthreads();
    }
}

// ---------- K4: combine -> inv_norm + logits ----------
__global__ __launch_bounds__(256) void k_fin_b(const float* __restrict__ bc,
                                               float* __restrict__ ws,
                                               float* __restrict__ out) {
    int tid = threadIdx.x;
    double red[5] = {0, 0, 0, 0, 0};
    const double* sp = (const double*)(ws + WS_SSQ);
    for (int i = tid; i < 2048; i += 256) red[4] += sp[i];
    const double* fp = (const double*)(ws + WS_FPART);
    if (tid < 32) {
        red[0] = fp[tid * 4 + 0];
        red[1] = fp[tid * 4 + 1];
        red[2] = fp[tid * 4 + 2];
        red[3] = fp[tid * 4 + 3];
    }
    __shared__ double sd[256];
    double tot[5];
    for (int q = 0; q < 5; ++q) {
        sd[tid] = red[q];
        __syncthreads();
        for (int s = 128; s; s >>= 1) {
            if (tid < s) sd[tid] += sd[tid + s];
            __syncthreads();
        }
        tot[q] = sd[0];
        __syncthreads();
    }
    if (tid == 0) {
        // ||S + lr*hh^T||^2 = ||S||^2 + 2*lr*(h^T S h) + lr^2*(||h||^2)^2
        double n2 = tot[4] + 2.0 * (double)LR * tot[0]
                  + (double)LR * (double)LR * tot[1] * tot[1];
        ws[WS_SCAL + 1] = (float)(1.0 / sqrt(n2));
        out[0] = (float)(tot[2] + (double)bc[0]);
        out[1] = (float)(tot[3] + (double)bc[1]);
    }
}

// ---------- K5: new_synapses, REVERSE rows (L3 MRU), NT stores ----------
__global__ __launch_bounds__(256) void k_scale(const float* __restrict__ S,
                                               const float* __restrict__ ws,
                                               float* __restrict__ out) {
    int row = (HD - 1) - blockIdx.x;   // reverse: MRU tail of S first -> L3 hits
    float hi  = ws[WS_HS + row] * LR;
    float inv = ws[WS_SCAL + 1];
    const f4* S4  = (const f4*)(S + (size_t)row * HD);
    const f4* hs4 = (const f4*)(ws + WS_HS);
    float* o = out + 2 + HD + (size_t)row * HD;  // 8B-aligned -> f2 stores
    int tid = threadIdx.x;
    if (hi != 0.f) {
#pragma unroll
        for (int it = 0; it < 8; ++it) {
            int j4 = it * 256 + tid;
            f4 s = S4[j4];
            f4 h = hs4[j4];
            f2 a  = {(s.x + hi * h.x) * inv, (s.y + hi * h.y) * inv};
            f2 bb = {(s.z + hi * h.z) * inv, (s.w + hi * h.w) * inv};
            f2* o2 = (f2*)(o + (size_t)j4 * 4);
            __builtin_nontemporal_store(a,  o2);
            __builtin_nontemporal_store(bb, o2 + 1);
        }
    } else {  // ~95% of rows: h_sparse[row]==0
#pragma unroll
        for (int it = 0; it < 8; ++it) {
            int j4 = it * 256 + tid;
            f4 s = S4[j4];
            f2 a  = {s.x * inv, s.y * inv};
            f2 bb = {s.z * inv, s.w * inv};
            f2* o2 = (f2*)(o + (size_t)j4 * 4);
            __builtin_nontemporal_store(a,  o2);
            __builtin_nontemporal_store(bb, o2 + 1);
        }
    }
}

extern "C" void kernel_launch(void* const* d_in, const int* in_sizes, int n_in,
                              void* d_out, int out_size, void* d_ws, size_t ws_size,
                              hipStream_t stream) {
    const float* x     = (const float*)d_in[0];
    const float* W_enc = (const float*)d_in[1];
    const float* b_enc = (const float*)d_in[2];
    const float* syn   = (const float*)d_in[3];
    const float* state = (const float*)d_in[4];
    const float* W_cls = (const float*)d_in[5];
    const float* b_cls = (const float*)d_in[6];
    float* out = (float*)d_out;
    float* ws  = (float*)d_ws;

    hipLaunchKernelGGL(k_main,   dim3(4096), dim3(256), 0, stream, x, W_enc, b_enc, syn, ws);
    hipLaunchKernelGGL(k_topk,   dim3(1),    dim3(256), 0, stream, ws);
    hipLaunchKernelGGL(k_ymvfin, dim3(32),   dim3(256), 0, stream, syn, state, W_cls, ws, out);
    hipLaunchKernelGGL(k_fin_b,  dim3(1),    dim3(256), 0, stream, b_cls, ws, out);
    hipLaunchKernelGGL(k_scale,  dim3(8192), dim3(256), 0, stream, syn, ws, out);
}